// Round 5
// baseline (111.555 us; speedup 1.0000x reference)
//
#include <hip/hip_runtime.h>
#include <math.h>

// Problem constants (match reference)
#define DIMD 1024
#define DIMV 4
#define NROWS 16384            // B*T = 4*4096
#define K_SCALE 0.03125f       // 1/sqrt(1024)
#define EPS_RMS (1e-10f / 1024.0f)
#define V_SIG_SCALE 4.0f

// native clang vector type (required by __builtin_nontemporal_*)
typedef float f32x4 __attribute__((ext_vector_type(4)));

// TWO waves per row (half-row per wave): lane l of half h owns
// d in {l + 64*(8h + j), j=0..7}. x-slice = 8 float4 = 32 VGPR.
// Cross-wave combine: 10 partial sums through 40 B of LDS + 1 barrier.
// Target: VGPR <= 64 so occupancy is thread-cap-limited (8 waves/SIMD).
// x loads / out stores NONTEMPORAL (read/write-once streams, no L3 alloc)
// so k/v/ctx (201 MB) stay L3-resident across graph replays.
__global__ __launch_bounds__(256) void ddre_kernel(
    const float* __restrict__ x,       // (NROWS, D, DV)
    const float* __restrict__ k_in,    // (NROWS, D)
    const float* __restrict__ v_in,    // (NROWS, D)
    const float* __restrict__ context, // (NROWS, D)
    const float* __restrict__ beta_w,  // (D)
    const float* __restrict__ beta_b,  // (1)
    const float* __restrict__ v_w,     // (DV, D)
    const float* __restrict__ v_b,     // (DV)
    float* __restrict__ out)           // (NROWS, D, DV)
{
    const int tid  = threadIdx.x;
    const int wave = tid >> 6;          // 0..3
    const int lane = tid & 63;
    const int half = wave & 1;          // which half-row this wave owns
    const int row  = (blockIdx.x << 1) | (wave >> 1);

    const float* xrow = x    + (size_t)row * (DIMD * DIMV);
    const float* krow = k_in + (size_t)row * DIMD;
    const int dbase = (half << 9) + lane;   // half*512 + lane

    // ---- x loads: 8 x 1KB coalesced, nontemporal ----
    f32x4 xr[8];
    #pragma unroll
    for (int j = 0; j < 8; ++j)
        xr[j] = __builtin_nontemporal_load(
                    (const f32x4*)(xrow + (size_t)(dbase + 64 * j) * DIMV));

    // k for owned d's
    float kr[8];
    #pragma unroll
    for (int j = 0; j < 8; ++j)
        kr[j] = krow[dbase + 64 * j];

    // ---- small dots over this wave's half: off = 4l + 256*(2h+m), m=0..1 ----
    const float* crow = context + (size_t)row * DIMD;
    const float* vrow = v_in    + (size_t)row * DIMD;
    float s_ctx = 0.0f;
    float s_v0 = 0.0f, s_v1 = 0.0f, s_v2 = 0.0f, s_v3 = 0.0f;
    #pragma unroll
    for (int m = 0; m < 2; ++m) {
        const int off = 4 * lane + 256 * ((half << 1) + m);
        const float4 c  = *(const float4*)(crow   + off);
        const float4 b  = *(const float4*)(beta_w + off);
        s_ctx += c.x*b.x + c.y*b.y + c.z*b.z + c.w*b.w;
        const float4 vv = *(const float4*)(vrow + off);
        const float4 w0 = *(const float4*)(v_w + 0 * DIMD + off);
        const float4 w1 = *(const float4*)(v_w + 1 * DIMD + off);
        const float4 w2 = *(const float4*)(v_w + 2 * DIMD + off);
        const float4 w3 = *(const float4*)(v_w + 3 * DIMD + off);
        s_v0 += vv.x*w0.x + vv.y*w0.y + vv.z*w0.z + vv.w*w0.w;
        s_v1 += vv.x*w1.x + vv.y*w1.y + vv.z*w1.z + vv.w*w1.w;
        s_v2 += vv.x*w2.x + vv.y*w2.y + vv.z*w2.z + vv.w*w2.w;
        s_v3 += vv.x*w3.x + vv.y*w3.y + vv.z*w3.z + vv.w*w3.w;
    }

    // ---- k^2 and k·x[:,v] over owned d's ----
    float s_k2 = 0.0f;
    float sx = 0.0f, sy = 0.0f, sz = 0.0f, sw = 0.0f;
    #pragma unroll
    for (int j = 0; j < 8; ++j) {
        s_k2 += kr[j] * kr[j];
        sx += kr[j] * xr[j].x;
        sy += kr[j] * xr[j].y;
        sz += kr[j] * xr[j].z;
        sw += kr[j] * xr[j].w;
    }

    // ---- intra-wave butterfly ----
    float s[10] = {s_k2, s_ctx, s_v0, s_v1, s_v2, s_v3, sx, sy, sz, sw};
    #pragma unroll
    for (int i = 0; i < 10; ++i) {
        #pragma unroll
        for (int off = 32; off >= 1; off >>= 1)
            s[i] += __shfl_xor(s[i], off, 64);
    }

    // ---- cross-wave (2 waves per row) combine via LDS ----
    __shared__ float red[4][10];
    if (lane == 0) {
        #pragma unroll
        for (int i = 0; i < 10; ++i) red[wave][i] = s[i];
    }
    __syncthreads();
    const int partner = wave ^ 1;
    float t[10];
    #pragma unroll
    for (int i = 0; i < 10; ++i) t[i] = s[i] + red[partner][i];

    // ---- scalar gates (redundant per lane, fp32) ----
    const float ms   = t[0] * (1.0f / (float)DIMD);
    const float rinv = rsqrtf(ms + EPS_RMS);
    const float beta = 2.0f / (1.0f + expf(-(t[1] + beta_b[0])));

    float delta[4];
    delta[0] = beta * (V_SIG_SCALE / (1.0f + expf(-(t[2] + v_b[0]))) - t[6] * rinv * K_SCALE) * K_SCALE;
    delta[1] = beta * (V_SIG_SCALE / (1.0f + expf(-(t[3] + v_b[1]))) - t[7] * rinv * K_SCALE) * K_SCALE;
    delta[2] = beta * (V_SIG_SCALE / (1.0f + expf(-(t[4] + v_b[2]))) - t[8] * rinv * K_SCALE) * K_SCALE;
    delta[3] = beta * (V_SIG_SCALE / (1.0f + expf(-(t[5] + v_b[3]))) - t[9] * rinv * K_SCALE) * K_SCALE;

    // ---- rank-1 update, write out (x still in registers, nontemporal) ----
    float* orow = out + (size_t)row * (DIMD * DIMV);
    #pragma unroll
    for (int j = 0; j < 8; ++j) {
        const float krms = kr[j] * rinv;
        f32x4 o;
        o.x = xr[j].x + krms * delta[0];
        o.y = xr[j].y + krms * delta[1];
        o.z = xr[j].z + krms * delta[2];
        o.w = xr[j].w + krms * delta[3];
        __builtin_nontemporal_store(o,
            (f32x4*)(orow + (size_t)(dbase + 64 * j) * DIMV));
    }
}

extern "C" void kernel_launch(void* const* d_in, const int* in_sizes, int n_in,
                              void* d_out, int out_size, void* d_ws, size_t ws_size,
                              hipStream_t stream) {
    const float* x       = (const float*)d_in[0];
    const float* k_in    = (const float*)d_in[1];
    const float* v_in    = (const float*)d_in[2];
    const float* context = (const float*)d_in[3];
    const float* beta_w  = (const float*)d_in[4];
    const float* beta_b  = (const float*)d_in[5];
    const float* v_w     = (const float*)d_in[6];
    const float* v_b     = (const float*)d_in[7];
    float* out = (float*)d_out;

    ddre_kernel<<<NROWS / 2, 256, 0, stream>>>(x, k_in, v_in, context,
                                               beta_w, beta_b, v_w, v_b, out);
}